// Round 1
// baseline (144.026 us; speedup 1.0000x reference)
//
#include <hip/hip_runtime.h>

typedef unsigned short u16;
typedef unsigned int u32;
typedef __attribute__((ext_vector_type(8))) short short8;   // 8 bf16 (MFMA A/B frag)
typedef __attribute__((ext_vector_type(4))) float f32x4;    // MFMA C/D frag
typedef __attribute__((ext_vector_type(4))) float fvec4;
typedef __attribute__((ext_vector_type(4))) u16 u16x4;

__device__ __forceinline__ u16 f2bf(float f) {
  u32 u = __float_as_uint(f);
  u += 0x7FFFu + ((u >> 16) & 1u);   // RTNE
  return (u16)(u >> 16);
}

// memory row index of token (Bg,h,w); rows of x / qkv are 256 / 768 elems.
// m = b*16384 + l*4096 + hx*512 + wy*64 + w   (b=Bg>>2, l=h&3, hx=(Bg&3)*2+(h>>5), wy=(h>>2)&7)
__device__ __forceinline__ int m_of(int Bg, int h, int w) {
  return ((Bg >> 2) << 14) | ((h & 3) << 12) | ((((Bg & 3) << 1) | (h >> 5)) << 9) |
         (((h >> 2) & 7) << 6) | w;
}

__device__ __forceinline__ f32x4 mfma16(short8 a, short8 b, f32x4 c) {
  return __builtin_amdgcn_mfma_f32_16x16x32_bf16(a, b, c, 0, 0, 0);
}

// ---------------- prep: convert W to bf16, materialize bias matrices ----------------
__global__ void k_prep(const float* __restrict__ qkv_w, const float* __restrict__ t0,
                       const float* __restrict__ t1, u16* __restrict__ wb,
                       float* __restrict__ bias4, float* __restrict__ bias8) {
  int tid = blockIdx.x * 256 + threadIdx.x;
  int stride = gridDim.x * 256;
  for (int i = tid; i < 768 * 256; i += stride) wb[i] = f2bf(qkv_w[i]);
  for (int i = tid; i < 4 * 64 * 64; i += stride) {
    int g = i >> 12, n = (i >> 6) & 63, m = i & 63;
    int di = (n >> 3) - (m >> 3) + 7, dj = (n & 7) - (m & 7) + 7;
    bias8[i] = t1[(di * 15 + dj) * 4 + g];
  }
  for (int i = tid; i < 4 * 16 * 16; i += stride) {
    int g = i >> 8, n = (i >> 4) & 15, m = i & 15;
    int di = (n >> 2) - (m >> 2) + 3, dj = (n & 3) - (m & 3) + 3;
    bias4[i] = t0[(di * 7 + dj) * 4 + g];
  }
}

// ---------------- QKV GEMM: [65536 x 256] x [256 x 768] -> bf16 qkv[m][768] ----------------
__global__ __launch_bounds__(256) void k_gemm(const float* __restrict__ x,
                                              const u16* __restrict__ wb,
                                              const float* __restrict__ qkv_b,
                                              u16* __restrict__ qkv) {
  __shared__ __align__(16) u16 As[128 * 72];  // A tile, pad 8 to kill bank conflicts
  __shared__ __align__(16) u16 Bs[128 * 72];  // B^T tile (rows = out col j, k contiguous)
  int bid = blockIdx.x;
  int mt = bid / 6, nt = bid - mt * 6;
  const int t = threadIdx.x;
  const int wid = t >> 6, l = t & 63;
  const int wm = (wid & 1) * 64, wn = (wid >> 1) * 64;
  const int lr = l & 15, lk4 = l >> 4;

  f32x4 acc[4][4];
  f32x4 z = {0.f, 0.f, 0.f, 0.f};
#pragma unroll
  for (int i = 0; i < 4; ++i)
#pragma unroll
    for (int j = 0; j < 4; ++j) acc[i][j] = z;

  const size_t xbase = (size_t)mt * 128 * 256;
  for (int kk0 = 0; kk0 < 256; kk0 += 64) {
    // stage A (f32 -> bf16)
    {
      int r0 = t >> 4, c = (t & 15) * 4;
#pragma unroll
      for (int p = 0; p < 8; ++p) {
        int r = p * 16 + r0;
        fvec4 v = *(const fvec4*)(x + xbase + (size_t)r * 256 + kk0 + c);
        u16x4 u;
        u[0] = f2bf(v[0]); u[1] = f2bf(v[1]); u[2] = f2bf(v[2]); u[3] = f2bf(v[3]);
        *(u16x4*)&As[r * 72 + c] = u;
      }
    }
    // stage B (already bf16)
    {
      int r0 = t >> 3, c = (t & 7) * 8;
#pragma unroll
      for (int p = 0; p < 4; ++p) {
        int jr = p * 32 + r0;
        short8 v = *(const short8*)(wb + (size_t)(nt * 128 + jr) * 256 + kk0 + c);
        *(short8*)&Bs[jr * 72 + c] = v;
      }
    }
    __syncthreads();
#pragma unroll
    for (int kk = 0; kk < 64; kk += 32) {
      short8 a[4], b[4];
#pragma unroll
      for (int i = 0; i < 4; ++i) a[i] = *(const short8*)&As[(wm + i * 16 + lr) * 72 + kk + lk4 * 8];
#pragma unroll
      for (int i = 0; i < 4; ++i) b[i] = *(const short8*)&Bs[(wn + i * 16 + lr) * 72 + kk + lk4 * 8];
#pragma unroll
      for (int i = 0; i < 4; ++i)
#pragma unroll
        for (int j = 0; j < 4; ++j) acc[i][j] = mfma16(a[i], b[j], acc[i][j]);
    }
    __syncthreads();
  }
  // epilogue: + bias, -> bf16
#pragma unroll
  for (int i = 0; i < 4; ++i)
#pragma unroll
    for (int j = 0; j < 4; ++j) {
      int col = nt * 128 + wn + j * 16 + lr;
      float bv = qkv_b[col];
#pragma unroll
      for (int r = 0; r < 4; ++r) {
        int row = mt * 128 + wm + i * 16 + lk4 * 4 + r;
        qkv[(size_t)row * 768 + col] = f2bf(acc[i][j][r] + bv);
      }
    }
}

// ---------------- attention ws=8 (group 1, channels 128..255) ----------------
// block = 1 window (1024 blocks), wave = head
__global__ __launch_bounds__(256) void k_attn8(const u16* __restrict__ qkv,
                                               const float* __restrict__ bias8,
                                               float* __restrict__ out) {
  __shared__ __align__(16) u16 vt[4 * 32 * 72];  // per-wave V^T [e][m] (pad 8)
  __shared__ __align__(16) u16 pl[4 * 64 * 72];  // per-wave P [n][m]; reused as O f32 [64][33]
  int bid = blockIdx.x;
  int Bg = bid >> 6, wi = (bid >> 3) & 7, wj = bid & 7;
  int h0 = wi * 8, w0 = wj * 8;
  int g = threadIdx.x >> 6, l = threadIdx.x & 63;
  int lr = l & 15, lk4 = l >> 4;
  u16* vtg = vt + g * (32 * 72);
  u16* plg = pl + g * (64 * 72);

  // load Q,K fragments straight from global (A-layout: row=l&15, k-chunk=(l>>4)*8)
  short8 aq[4], bk[4];
#pragma unroll
  for (int tn = 0; tn < 4; ++tn) {
    int n = tn * 16 + lr;
    int h = h0 + (n >> 3), w = w0 + (n & 7);
    const u16* row = qkv + (size_t)m_of(Bg, h, w) * 768;
    aq[tn] = *(const short8*)(row + 128 + g * 32 + lk4 * 8);
    bk[tn] = *(const short8*)(row + 384 + g * 32 + lk4 * 8);
  }
  // stage V^T: lane l owns token m=l
  {
    int h = h0 + (l >> 3), w = w0 + (l & 7);
    const u16* vrow = qkv + (size_t)m_of(Bg, h, w) * 768 + 640 + g * 32;
    short8 v0 = *(const short8*)(vrow);
    short8 v1 = *(const short8*)(vrow + 8);
    short8 v2 = *(const short8*)(vrow + 16);
    short8 v3 = *(const short8*)(vrow + 24);
#pragma unroll
    for (int j = 0; j < 8; ++j) {
      vtg[(0 + j) * 72 + l] = (u16)v0[j];
      vtg[(8 + j) * 72 + l] = (u16)v1[j];
      vtg[(16 + j) * 72 + l] = (u16)v2[j];
      vtg[(24 + j) * 72 + l] = (u16)v3[j];
    }
  }
  // S = q k^T  (16 MFMAs)
  f32x4 z = {0.f, 0.f, 0.f, 0.f};
  f32x4 s[4][4];
#pragma unroll
  for (int tn = 0; tn < 4; ++tn)
#pragma unroll
    for (int tm = 0; tm < 4; ++tm) s[tn][tm] = mfma16(aq[tn], bk[tm], z);

  const float scale = 0.17677669529663687f;  // 1/sqrt(32)
#pragma unroll
  for (int tn = 0; tn < 4; ++tn)
#pragma unroll
    for (int tm = 0; tm < 4; ++tm)
#pragma unroll
      for (int r = 0; r < 4; ++r) {
        int n = tn * 16 + lk4 * 4 + r, m = tm * 16 + lr;
        s[tn][tm][r] = s[tn][tm][r] * scale + bias8[(g * 64 + n) * 64 + m];
      }
  // softmax over m (row n lives in 16 lanes sharing l>>4)
  float invden[4][4];
#pragma unroll
  for (int tn = 0; tn < 4; ++tn)
#pragma unroll
    for (int r = 0; r < 4; ++r) {
      float mx = fmaxf(fmaxf(s[tn][0][r], s[tn][1][r]), fmaxf(s[tn][2][r], s[tn][3][r]));
#pragma unroll
      for (int d = 1; d < 16; d <<= 1) mx = fmaxf(mx, __shfl_xor(mx, d));
      float sum = 0.f;
#pragma unroll
      for (int tm = 0; tm < 4; ++tm) {
        float p = __expf(s[tn][tm][r] - mx);
        s[tn][tm][r] = p;
        sum += p;
      }
#pragma unroll
      for (int d = 1; d < 16; d <<= 1) sum += __shfl_xor(sum, d);
      invden[tn][r] = 1.f / sum;
    }
  // P -> LDS (bf16)
#pragma unroll
  for (int tn = 0; tn < 4; ++tn)
#pragma unroll
    for (int tm = 0; tm < 4; ++tm)
#pragma unroll
      for (int r = 0; r < 4; ++r)
        plg[(tn * 16 + lk4 * 4 + r) * 72 + tm * 16 + lr] = f2bf(s[tn][tm][r]);
  __syncthreads();
  // O = P V  (16 MFMAs)
  f32x4 o[4][2];
#pragma unroll
  for (int tn = 0; tn < 4; ++tn) { o[tn][0] = z; o[tn][1] = z; }
#pragma unroll
  for (int kc = 0; kc < 2; ++kc) {
    short8 pa[4], vb[2];
#pragma unroll
    for (int tn = 0; tn < 4; ++tn)
      pa[tn] = *(const short8*)&plg[(tn * 16 + lr) * 72 + kc * 32 + lk4 * 8];
#pragma unroll
    for (int te = 0; te < 2; ++te)
      vb[te] = *(const short8*)&vtg[(te * 16 + lr) * 72 + kc * 32 + lk4 * 8];
#pragma unroll
    for (int tn = 0; tn < 4; ++tn)
#pragma unroll
      for (int te = 0; te < 2; ++te) o[tn][te] = mfma16(pa[tn], vb[te], o[tn][te]);
  }
  __syncthreads();
  // scale by 1/denom, transpose O through LDS (overlay on plg)
  float* ol = (float*)plg;  // [64][33]
#pragma unroll
  for (int tn = 0; tn < 4; ++tn)
#pragma unroll
    for (int te = 0; te < 2; ++te)
#pragma unroll
      for (int r = 0; r < 4; ++r) {
        int n = tn * 16 + lk4 * 4 + r;
        ol[n * 33 + te * 16 + lr] = o[tn][te][r] * invden[tn][r];
      }
  __syncthreads();
  // store: lane = token, loop e -> 32B-chunk coalesced runs along w
  {
    int h = h0 + (l >> 3), w = w0 + (l & 7);
    size_t base = ((size_t)(Bg >> 2)) * 4194304 + (size_t)(((Bg & 3) * 2 + (h >> 5))) * 131072 +
                  (size_t)(((h >> 2) & 7)) * 16384 + (size_t)((h & 3) * 64 + w);
#pragma unroll
    for (int e = 0; e < 32; ++e) {
      int c = 128 + g * 32 + e;
      size_t idx = base + (size_t)(c >> 6) * 1048576 + (size_t)((c >> 3) & 7) * 2048 +
                   (size_t)(c & 7) * 256;
      out[idx] = ol[l * 33 + e];
    }
  }
}

// ---------------- attention ws=4 (group 0, channels 0..127) ----------------
// block = 4 windows (1024 blocks), wave = window, heads looped
__global__ __launch_bounds__(256) void k_attn4(const u16* __restrict__ qkv,
                                               const float* __restrict__ bias4,
                                               float* __restrict__ out) {
  __shared__ __align__(16) u16 vt[4 * 32 * 40];   // per-wave V^T [e][m0..32] (m 16..31 zero)
  __shared__ __align__(16) u16 pl[4 * 16 * 40];   // per-wave P [n][m0..32] (m 16..31 zero)
  __shared__ __align__(16) float ol[4 * 16 * 33]; // per-wave O
  int wv = threadIdx.x >> 6, l = threadIdx.x & 63;
  int wid = blockIdx.x * 4 + wv;
  int Bg = wid >> 8, wi = (wid >> 4) & 15, wj = wid & 15;
  int h0 = wi * 4, w0 = wj * 4;
  int lr = l & 15, lk4 = l >> 4;
  u16* vtw = vt + wv * (32 * 40);
  u16* plw = pl + wv * (16 * 40);
  float* olw = ol + wv * (16 * 33);
  f32x4 z = {0.f, 0.f, 0.f, 0.f};
  short8 z8 = {0, 0, 0, 0, 0, 0, 0, 0};
  const float scale = 0.17677669529663687f;

  // per-lane token addresses
  int hq = h0 + (lr >> 2), wq = w0 + (lr & 3);
  const u16* rowq = qkv + (size_t)m_of(Bg, hq, wq) * 768;

  for (int g = 0; g < 4; ++g) {
    short8 aq = *(const short8*)(rowq + g * 32 + lk4 * 8);
    short8 bk = *(const short8*)(rowq + 256 + g * 32 + lk4 * 8);
    // stage V^T: lane = (token lr) x (e-chunk lk4)
    {
      short8 v = *(const short8*)(rowq + 512 + g * 32 + lk4 * 8);
#pragma unroll
      for (int j = 0; j < 8; ++j) vtw[(lk4 * 8 + j) * 40 + lr] = (u16)v[j];
      // zero pad m in [16,32)
      *(short8*)&vtw[(l >> 1) * 40 + 16 + (l & 1) * 8] = z8;
    }
    // S (1 MFMA), C rows n = lk4*4+r, cols m = lr
    f32x4 s = mfma16(aq, bk, z);
#pragma unroll
    for (int r = 0; r < 4; ++r) {
      int n = lk4 * 4 + r;
      s[r] = s[r] * scale + bias4[(g * 16 + n) * 16 + lr];
    }
    float invden[4];
#pragma unroll
    for (int r = 0; r < 4; ++r) {
      float mx = s[r];
#pragma unroll
      for (int d = 1; d < 16; d <<= 1) mx = fmaxf(mx, __shfl_xor(mx, d));
      float p = __expf(s[r] - mx);
      s[r] = p;
      float sum = p;
#pragma unroll
      for (int d = 1; d < 16; d <<= 1) sum += __shfl_xor(sum, d);
      invden[r] = 1.f / sum;
    }
    // P -> LDS + zero pad
#pragma unroll
    for (int r = 0; r < 4; ++r) plw[(lk4 * 4 + r) * 40 + lr] = f2bf(s[r]);
    *(u16x4*)&plw[lr * 40 + 16 + lk4 * 4] = (u16x4){0, 0, 0, 0};
    __syncthreads();
    // O = P V : 2 MFMAs (te halves), K zero-padded to 32
    f32x4 o[2];
#pragma unroll
    for (int te = 0; te < 2; ++te) {
      short8 pa = *(const short8*)&plw[lr * 40 + lk4 * 8];
      short8 vb = *(const short8*)&vtw[(te * 16 + lr) * 40 + lk4 * 8];
      o[te] = mfma16(pa, vb, z);
    }
#pragma unroll
    for (int te = 0; te < 2; ++te)
#pragma unroll
      for (int r = 0; r < 4; ++r) {
        int n = lk4 * 4 + r;
        olw[n * 33 + te * 16 + lr] = o[te][r] * invden[r];
      }
    __syncthreads();
    // store: lane = (token lr) x (e-chunk lk4)
    {
      int h = h0 + (lr >> 2), w = w0 + (lr & 3);
      size_t base = ((size_t)(Bg >> 2)) * 4194304 +
                    (size_t)(((Bg & 3) * 2 + (h >> 5))) * 131072 +
                    (size_t)(((h >> 2) & 7)) * 16384 + (size_t)((h & 3) * 64 + w);
#pragma unroll
      for (int ee = 0; ee < 8; ++ee) {
        int e = lk4 * 8 + ee;
        int c = g * 32 + e;
        size_t idx = base + (size_t)(c >> 6) * 1048576 + (size_t)((c >> 3) & 7) * 2048 +
                     (size_t)(c & 7) * 256;
        out[idx] = olw[lr * 33 + e];
      }
    }
    __syncthreads();
  }
}

extern "C" void kernel_launch(void* const* d_in, const int* in_sizes, int n_in,
                              void* d_out, int out_size, void* d_ws, size_t ws_size,
                              hipStream_t stream) {
  const float* x = (const float*)d_in[0];
  const float* qkv_w = (const float*)d_in[1];
  const float* qkv_b = (const float*)d_in[2];
  const float* t0 = (const float*)d_in[3];
  const float* t1 = (const float*)d_in[4];
  float* out = (float*)d_out;
  char* ws = (char*)d_ws;

  u16* qkv = (u16*)ws;                          // 65536*768*2      = 100663296 B
  u16* wb = (u16*)(ws + 100663296);             // 768*256*2        = 393216 B
  float* bias8 = (float*)(ws + 101056512);      // 4*64*64*4        = 65536 B
  float* bias4 = (float*)(ws + 101122048);      // 4*16*16*4        = 4096 B

  k_prep<<<256, 256, 0, stream>>>(qkv_w, t0, t1, wb, bias4, bias8);
  k_gemm<<<3072, 256, 0, stream>>>(x, wb, qkv_b, qkv);
  k_attn8<<<1024, 256, 0, stream>>>(qkv, bias8, out);
  k_attn4<<<1024, 256, 0, stream>>>(qkv, bias4, out);
}